// Round 6
// baseline (128.637 us; speedup 1.0000x reference)
//
#include <hip/hip_runtime.h>
#include <math.h>

#define BSZ 512
#define DD 2048
#define KK 128
#define PP 5
#define NCOL (KK * PP)   // 640
#define OUTW (DD + KK)   // 2176
#define LOG2E 1.4426950408889634f

#define QSPLIT 8         // pairwise b2 chunks

typedef __attribute__((ext_vector_type(8))) short bf16x8;
typedef __attribute__((ext_vector_type(4))) float f32x4;

// ws layout (floats):
#define WS_NORM 0
#define WS_ACTV (WS_NORM + NCOL)                      // 640
#define WS_FPART (WS_ACTV + BSZ * NCOL)               // 328320
#define WS_XB (WS_FPART + QSPLIT * KK * BSZ)          // 852608 (512*2048 ushort)
#define WS_THT (WS_XB + BSZ * DD / 2)                 // 1376896 (640*2048 ushort)
// total ~8.1 MB

__device__ inline ushort f2b(float f) {               // f32 -> bf16 RNE
    unsigned u = __float_as_uint(f);
    u += 0x7FFF + ((u >> 16) & 1);
    return (ushort)(u >> 16);
}

// XOR-swizzled LDS index (ushort units): flips 16B-slot bits 3..5 with row&7.
// Staging: 16 lanes same row, 16 slots -> all 32 banks. Frag read: rows 0..7
// -> 8 distinct slots (128B = all banks); 2-way wave alias = free (m136).
#define SWZ(r, c) ((((r) * 128) + ((c) ^ (((r) & 7) << 3))))

// ---------------------------------------------------------------------------
// Kernel 1 (prep): [0,80) norm = colsum theta^2; [80,400) theta -> bf16
// transposed [640 n][2048 k]; [400,656) x -> bf16 [512][2048].
// ---------------------------------------------------------------------------
__global__ __launch_bounds__(256) void prep_kernel(const float* __restrict__ theta,
                                                   const float* __restrict__ x,
                                                   float* __restrict__ norm,
                                                   ushort* __restrict__ thT,
                                                   ushort* __restrict__ xb) {
    __shared__ float partial[32][8];
    __shared__ ushort sT[64][68];   // [n][k] tile; stride 68: write 8-way, read 2-way

    const int bid = blockIdx.x;
    const int t   = threadIdx.x;

    if (bid < 80) {                 // ---- norm ----
        const int c8  = bid * 8;
        const int col = c8 + (t & 7);
        const int g   = t >> 3;
        const float* p = theta + (size_t)g * NCOL + col;
        float s = 0.f;
#pragma unroll
        for (int j = 0; j < 64; ++j) {
            float v = p[(size_t)j * 32 * NCOL];
            s += v * v;
        }
        partial[g][t & 7] = s;
        __syncthreads();
        if (t < 8) {
            float acc = 0.f;
#pragma unroll
            for (int gg = 0; gg < 32; ++gg) acc += partial[gg][t];
            norm[c8 + t] = acc;
        }
    } else if (bid < 400) {         // ---- theta transpose+convert, 64x64 tiles ----
        const int tb    = bid - 80;        // 0..319 = 32 ktiles x 10 ntiles
        const int kz    = (tb & 31) * 64;
        const int nz    = (tb >> 5) * 64;
        const int c4    = t & 15;          // n-quad
        const int rbase = t >> 4;          // k-row base
#pragma unroll
        for (int i = 0; i < 4; ++i) {
            int r = rbase + i * 16;
            float4 v = *(const float4*)&theta[(size_t)(kz + r) * NCOL + nz + c4 * 4];
            sT[c4 * 4 + 0][r] = f2b(v.x);
            sT[c4 * 4 + 1][r] = f2b(v.y);
            sT[c4 * 4 + 2][r] = f2b(v.z);
            sT[c4 * 4 + 3][r] = f2b(v.w);
        }
        __syncthreads();
#pragma unroll
        for (int i = 0; i < 2; ++i) {
            int slot = t + i * 256;
            int rr   = slot >> 3;          // n row 0..63
            int cc   = (slot & 7) * 8;     // k col
            ushort4 w0 = *(const ushort4*)&sT[rr][cc];
            ushort4 w1 = *(const ushort4*)&sT[rr][cc + 4];
            ushort* dst = &thT[(size_t)(nz + rr) * DD + kz + cc];
            *(ushort4*)&dst[0] = w0;
            *(ushort4*)&dst[4] = w1;
        }
    } else {                        // ---- x convert ----
        const int b2 = bid - 400;          // 0..255
#pragma unroll
        for (int i = 0; i < 4; ++i) {
            int base = b2 * 4096 + i * 1024 + t * 4;
            float4 v = *(const float4*)&x[base];
            ushort4 w;
            w.x = f2b(v.x); w.y = f2b(v.y); w.z = f2b(v.z); w.w = f2b(v.w);
            *(ushort4*)&xb[base] = w;
        }
    }
}

// ---------------------------------------------------------------------------
// Kernel 2: full-K MFMA GEMM (no split-K), scale folded into epilogue,
// writes actv directly. Blocks [0,80): 64m x 64n tile, 4 waves 2x2, each
// wave 32x32 via mfma_f32_16x16x32_bf16; K=2048 in 16 staged chunks of 128,
// reg-prefetched, XOR-swizzled LDS (conflict-free; pad-136 measured 4-way,
// SQ_LDS_BANK_CONFLICT=327680). Blocks [80,160): x -> out[:, :D] copy.
// ---------------------------------------------------------------------------
__global__ __launch_bounds__(256) void gemm_kernel(const ushort* __restrict__ xb,
                                                   const ushort* __restrict__ thT,
                                                   const float* __restrict__ norm,
                                                   const float* __restrict__ lws,
                                                   float* __restrict__ actv,
                                                   const float* __restrict__ x,
                                                   float* __restrict__ out) {
    __shared__ ushort lA[64 * 128];   // 16 KiB, swizzled
    __shared__ ushort lB[64 * 128];

    const int bx = blockIdx.x;
    if (bx >= 80) {
        const int bid = bx - 80;        // 0..79
        for (int i = bid * 256 + threadIdx.x; i < BSZ * (DD / 4); i += 80 * 256) {
            int r = i >> 9;
            int c = i & 511;
            float4 v = *(const float4*)&x[(size_t)r * DD + c * 4];
            *(float4*)&out[(size_t)r * OUTW + c * 4] = v;
        }
        return;
    }

    const int t    = threadIdx.x;
    const int lane = t & 63;
    const int wave = t >> 6;
    const int bn   = (bx % 10) * 64;
    const int bm   = (bx / 10) * 64;

    const ushort* gA = xb  + (size_t)bm * DD;
    const ushort* gB = thT + (size_t)bn * DD;

    f32x4 acc[2][2] = {};

    const int srr = t >> 4;          // staging row  (slot layout: 4 x 256)
    const int sss = t & 15;          // staging slot

    uint4 va[4], vb[4];
#pragma unroll
    for (int i = 0; i < 4; ++i) {
        int rr = srr + i * 16;
        va[i] = *(const uint4*)&gA[(size_t)rr * DD + sss * 8];
        vb[i] = *(const uint4*)&gB[(size_t)rr * DD + sss * 8];
    }

    const int fr = lane & 15;
    const int g  = lane >> 4;
    const int mr = (wave >> 1) * 32 + fr;
    const int nr = (wave & 1) * 32 + fr;

    for (int c = 0; c < 16; ++c) {
        __syncthreads();   // previous chunk's LDS reads complete
#pragma unroll
        for (int i = 0; i < 4; ++i) {
            int rr = srr + i * 16;
            *(uint4*)&lA[SWZ(rr, sss * 8)] = va[i];
            *(uint4*)&lB[SWZ(rr, sss * 8)] = vb[i];
        }
        __syncthreads();
        if (c != 15) {
            const int kn = (c + 1) * 128;
#pragma unroll
            for (int i = 0; i < 4; ++i) {
                int rr = srr + i * 16;
                va[i] = *(const uint4*)&gA[(size_t)rr * DD + kn + sss * 8];
                vb[i] = *(const uint4*)&gB[(size_t)rr * DD + kn + sss * 8];
            }
        }
#pragma unroll
        for (int ks = 0; ks < 4; ++ks) {
            const int kc = ks * 32 + g * 8;
            bf16x8 a0 = *(const bf16x8*)&lA[SWZ(mr,      kc)];
            bf16x8 a1 = *(const bf16x8*)&lA[SWZ(mr + 16, kc)];
            bf16x8 b0 = *(const bf16x8*)&lB[SWZ(nr,      kc)];
            bf16x8 b1 = *(const bf16x8*)&lB[SWZ(nr + 16, kc)];
            acc[0][0] = __builtin_amdgcn_mfma_f32_16x16x32_bf16(a0, b0, acc[0][0], 0, 0, 0);
            acc[0][1] = __builtin_amdgcn_mfma_f32_16x16x32_bf16(a0, b1, acc[0][1], 0, 0, 0);
            acc[1][0] = __builtin_amdgcn_mfma_f32_16x16x32_bf16(a1, b0, acc[1][0], 0, 0, 0);
            acc[1][1] = __builtin_amdgcn_mfma_f32_16x16x32_bf16(a1, b1, acc[1][1], 0, 0, 0);
        }
    }

    // epilogue: fold scale = exp(lws)/norm * log2e; C/D map col=lane&15,
    // row=(lane>>4)*4+reg [m89-verified]
    float sc[2];
#pragma unroll
    for (int nt = 0; nt < 2; ++nt) {
        int col = bn + (wave & 1) * 32 + nt * 16 + fr;
        sc[nt] = __builtin_amdgcn_exp2f(lws[col] * LOG2E) *
                 __builtin_amdgcn_rsqf(norm[col]) * LOG2E;
    }
#pragma unroll
    for (int mt = 0; mt < 2; ++mt)
#pragma unroll
        for (int nt = 0; nt < 2; ++nt) {
            int row = bm + (wave >> 1) * 32 + mt * 16 + g * 4;
            int col = bn + (wave & 1) * 32 + nt * 16 + fr;
            float* dst = actv + (size_t)row * NCOL + col;
#pragma unroll
            for (int reg = 0; reg < 4; ++reg)
                dst[(size_t)reg * NCOL] = acc[mt][nt][reg] * sc[nt];
        }
}

// ---------------------------------------------------------------------------
// Kernel 3: pairwise L1 -> exp2 -> partial rowsum over 64-wide b2 chunk.
// 256 threads, 2 b-rows/thread. Coalesced f_part stores (NO device-scope
// atomics: write-through to HBM on non-coherent-L2 gfx950, +30us measured).
// ---------------------------------------------------------------------------
__global__ __launch_bounds__(256) void pairwise_kernel(const float* __restrict__ actv,
                                                       float* __restrict__ f_part) {
    const int k   = blockIdx.x;    // 0..127
    const int q   = blockIdx.y;    // 0..7
    const int tid = threadIdx.x;   // 0..255

    __shared__ float sB[64][8];    // 2 KiB, rows 32B-aligned

    for (int i = tid; i < 64 * PP; i += 256) {   // 320 entries
        int r = i / PP;
        int p = i - r * PP;
        sB[r][p] = actv[(size_t)(q * 64 + r) * NCOL + k * PP + p];
    }

    float a[2][PP];
#pragma unroll
    for (int r = 0; r < 2; ++r) {
        const float* ap = &actv[(size_t)(tid + r * 256) * NCOL + k * PP];
#pragma unroll
        for (int p = 0; p < PP; ++p) a[r][p] = ap[p];
    }
    __syncthreads();

    float acc[2] = {0.f, 0.f};
#pragma unroll 4
    for (int j = 0; j < 64; ++j) {
        const float4 v  = *(const float4*)&sB[j][0];
        const float  v4 = sB[j][4];
#pragma unroll
        for (int r = 0; r < 2; ++r) {
            float s = fabsf(a[r][0] - v.x) + fabsf(a[r][1] - v.y) +
                      fabsf(a[r][2] - v.z) + fabsf(a[r][3] - v.w) +
                      fabsf(a[r][4] - v4);
            acc[r] += __builtin_amdgcn_exp2f(-s);   // actv pre-scaled by log2e
        }
    }

    float* fp = f_part + ((size_t)q * KK + k) * BSZ;
    fp[tid]       = acc[0];
    fp[tid + 256] = acc[1];
}

// ---------------------------------------------------------------------------
// Kernel 4: reduce f_part (L2-resident 2MB) into out[:, D:].
// ---------------------------------------------------------------------------
__global__ __launch_bounds__(256) void freduce_kernel(const float* __restrict__ f_part,
                                                      const float* __restrict__ bias,
                                                      float* __restrict__ out) {
    int i = blockIdx.x * 256 + threadIdx.x;   // 0..65535
    int k = i >> 9;
    int b = i & 511;
    float s = 0.f;
#pragma unroll
    for (int q = 0; q < QSPLIT; ++q)
        s += f_part[((size_t)q * KK + k) * BSZ + b];
    out[(size_t)b * OUTW + DD + k] = s - 1.0f + bias[k];
}

// ---------------------------------------------------------------------------
extern "C" void kernel_launch(void* const* d_in, const int* in_sizes, int n_in,
                              void* d_out, int out_size, void* d_ws, size_t ws_size,
                              hipStream_t stream) {
    const float* x     = (const float*)d_in[0];   // [512, 2048]
    const float* theta = (const float*)d_in[1];   // [2048, 128, 5]
    const float* lws   = (const float*)d_in[2];   // [128, 5]
    const float* bias  = (const float*)d_in[3];   // [128]
    float* out = (float*)d_out;                   // [512, 2176]

    float* ws     = (float*)d_ws;
    float* norm   = ws + WS_NORM;
    float* actv   = ws + WS_ACTV;
    float* f_part = ws + WS_FPART;
    ushort* xb    = (ushort*)(ws + WS_XB);
    ushort* thT   = (ushort*)(ws + WS_THT);

    prep_kernel<<<656, 256, 0, stream>>>(theta, x, norm, thT, xb);
    gemm_kernel<<<160, 256, 0, stream>>>(xb, thT, norm, lws, actv, x, out);
    pairwise_kernel<<<dim3(KK, QSPLIT), 256, 0, stream>>>(actv, f_part);
    freduce_kernel<<<256, 256, 0, stream>>>(f_part, bias, out);
}

// Round 7
// 104.008 us; speedup vs baseline: 1.2368x; 1.2368x over previous
//
#include <hip/hip_runtime.h>
#include <math.h>

#define BSZ 512
#define DD 2048
#define KK 128
#define PP 5
#define NCOL (KK * PP)   // 640
#define OUTW (DD + KK)   // 2176
#define LOG2E 1.4426950408889634f

#define KSPLIT 16
#define GK (DD / KSPLIT) // 128 k-depth per split
#define QSPLIT 8         // pairwise b2 chunks

typedef __attribute__((ext_vector_type(8))) short bf16x8;
typedef __attribute__((ext_vector_type(4))) float f32x4;

// ws layout (floats):
#define WS_NORM 0
#define WS_ACTV (WS_NORM + NCOL)                      // 640
#define WS_FPART (WS_ACTV + BSZ * NCOL)               // 328320
#define WS_XB (WS_FPART + QSPLIT * KK * BSZ)          // 852608 (512*2048 ushort)
#define WS_THT (WS_XB + BSZ * DD / 2)                 // 1376896 (640*2048 ushort)
#define WS_PART (WS_THT + NCOL * DD / 2)              // 2032256
// part = 16*512*640 floats; total ~29 MB (ws = 256 MiB poison buffer, fine)

__device__ inline ushort f2b(float f) {               // f32 -> bf16 RNE
    unsigned u = __float_as_uint(f);
    u += 0x7FFF + ((u >> 16) & 1);
    return (ushort)(u >> 16);
}

// XOR-swizzled LDS index (ushort units). Conflicts measured layout-invariant
// (~256 cyc/chunk, ~1.7us total) -- kept, not the bottleneck.
#define SWZ(r, c) ((((r) * 128) + ((c) ^ (((r) & 7) << 3))))

// ---------------------------------------------------------------------------
// Kernel 1 (prep): [0,80) norm = colsum theta^2; [80,400) theta -> bf16
// transposed [640 n][2048 k]; [400,656) x -> bf16 [512][2048].
// ---------------------------------------------------------------------------
__global__ __launch_bounds__(256) void prep_kernel(const float* __restrict__ theta,
                                                   const float* __restrict__ x,
                                                   float* __restrict__ norm,
                                                   ushort* __restrict__ thT,
                                                   ushort* __restrict__ xb) {
    __shared__ float partial[32][8];
    __shared__ ushort sT[64][68];   // [n][k] tile; stride 68: write 8-way, read 2-way

    const int bid = blockIdx.x;
    const int t   = threadIdx.x;

    if (bid < 80) {                 // ---- norm ----
        const int c8  = bid * 8;
        const int col = c8 + (t & 7);
        const int g   = t >> 3;
        const float* p = theta + (size_t)g * NCOL + col;
        float s = 0.f;
#pragma unroll
        for (int j = 0; j < 64; ++j) {
            float v = p[(size_t)j * 32 * NCOL];
            s += v * v;
        }
        partial[g][t & 7] = s;
        __syncthreads();
        if (t < 8) {
            float acc = 0.f;
#pragma unroll
            for (int gg = 0; gg < 32; ++gg) acc += partial[gg][t];
            norm[c8 + t] = acc;
        }
    } else if (bid < 400) {         // ---- theta transpose+convert, 64x64 tiles ----
        const int tb    = bid - 80;        // 0..319 = 32 ktiles x 10 ntiles
        const int kz    = (tb & 31) * 64;
        const int nz    = (tb >> 5) * 64;
        const int c4    = t & 15;          // n-quad
        const int rbase = t >> 4;          // k-row base
#pragma unroll
        for (int i = 0; i < 4; ++i) {
            int r = rbase + i * 16;
            float4 v = *(const float4*)&theta[(size_t)(kz + r) * NCOL + nz + c4 * 4];
            sT[c4 * 4 + 0][r] = f2b(v.x);
            sT[c4 * 4 + 1][r] = f2b(v.y);
            sT[c4 * 4 + 2][r] = f2b(v.z);
            sT[c4 * 4 + 3][r] = f2b(v.w);
        }
        __syncthreads();
#pragma unroll
        for (int i = 0; i < 2; ++i) {
            int slot = t + i * 256;
            int rr   = slot >> 3;          // n row 0..63
            int cc   = (slot & 7) * 8;     // k col
            ushort4 w0 = *(const ushort4*)&sT[rr][cc];
            ushort4 w1 = *(const ushort4*)&sT[rr][cc + 4];
            ushort* dst = &thT[(size_t)(nz + rr) * DD + kz + cc];
            *(ushort4*)&dst[0] = w0;
            *(ushort4*)&dst[4] = w1;
        }
    } else {                        // ---- x convert ----
        const int b2 = bid - 400;          // 0..255
#pragma unroll
        for (int i = 0; i < 4; ++i) {
            int base = b2 * 4096 + i * 1024 + t * 4;
            float4 v = *(const float4*)&x[base];
            ushort4 w;
            w.x = f2b(v.x); w.y = f2b(v.y); w.z = f2b(v.z); w.w = f2b(v.w);
            *(ushort4*)&xb[base] = w;
        }
    }
}

// ---------------------------------------------------------------------------
// Kernel 2: split-K MFMA GEMM, ONE chunk per block (straight-line, single
// barrier, no pipeline to stall). KSPLIT=16 -> 1280 compute blocks = 5/CU
// (LDS 32KB x 5 = 160KB): resident-block TLP hides global+LDS latency.
// r6 lesson: 80 blocks = 1 wave/SIMD = latency-serial 43.5us, Occ 3.2%.
// Blocks [1280,1360): x -> out[:, :D] copy (overlapped BW work).
// ---------------------------------------------------------------------------
__global__ __launch_bounds__(256) void gemm_kernel(const ushort* __restrict__ xb,
                                                   const ushort* __restrict__ thT,
                                                   float* __restrict__ part,
                                                   const float* __restrict__ x,
                                                   float* __restrict__ out) {
    __shared__ ushort lA[64 * 128];   // 16 KiB, swizzled
    __shared__ ushort lB[64 * 128];

    const int bx = blockIdx.x;
    if (bx >= 1280) {
        const int bid = bx - 1280;      // 0..79
        for (int i = bid * 256 + threadIdx.x; i < BSZ * (DD / 4); i += 80 * 256) {
            int r = i >> 9;
            int c = i & 511;
            float4 v = *(const float4*)&x[(size_t)r * DD + c * 4];
            *(float4*)&out[(size_t)r * OUTW + c * 4] = v;
        }
        return;
    }

    const int t    = threadIdx.x;
    const int lane = t & 63;
    const int wave = t >> 6;
    const int tile = bx % 80;          // 80 tiles per z-slice
    const int z    = bx / 80;          // 0..15
    const int bn   = (tile % 10) * 64;
    const int bm   = (tile / 10) * 64;
    const int kz   = z * GK;

    const ushort* gA = xb  + (size_t)bm * DD + kz;
    const ushort* gB = thT + (size_t)bn * DD + kz;

    const int srr = t >> 4;          // staging row base
    const int sss = t & 15;          // staging slot

    uint4 va[4], vb[4];
#pragma unroll
    for (int i = 0; i < 4; ++i) {
        int rr = srr + i * 16;
        va[i] = *(const uint4*)&gA[(size_t)rr * DD + sss * 8];
        vb[i] = *(const uint4*)&gB[(size_t)rr * DD + sss * 8];
    }
#pragma unroll
    for (int i = 0; i < 4; ++i) {
        int rr = srr + i * 16;
        *(uint4*)&lA[SWZ(rr, sss * 8)] = va[i];
        *(uint4*)&lB[SWZ(rr, sss * 8)] = vb[i];
    }
    __syncthreads();

    const int fr = lane & 15;
    const int g  = lane >> 4;
    const int mr = (wave >> 1) * 32 + fr;
    const int nr = (wave & 1) * 32 + fr;

    f32x4 acc[2][2] = {};
#pragma unroll
    for (int ks = 0; ks < 4; ++ks) {
        const int kc = ks * 32 + g * 8;
        bf16x8 a0 = *(const bf16x8*)&lA[SWZ(mr,      kc)];
        bf16x8 a1 = *(const bf16x8*)&lA[SWZ(mr + 16, kc)];
        bf16x8 b0 = *(const bf16x8*)&lB[SWZ(nr,      kc)];
        bf16x8 b1 = *(const bf16x8*)&lB[SWZ(nr + 16, kc)];
        acc[0][0] = __builtin_amdgcn_mfma_f32_16x16x32_bf16(a0, b0, acc[0][0], 0, 0, 0);
        acc[0][1] = __builtin_amdgcn_mfma_f32_16x16x32_bf16(a0, b1, acc[0][1], 0, 0, 0);
        acc[1][0] = __builtin_amdgcn_mfma_f32_16x16x32_bf16(a1, b0, acc[1][0], 0, 0, 0);
        acc[1][1] = __builtin_amdgcn_mfma_f32_16x16x32_bf16(a1, b1, acc[1][1], 0, 0, 0);
    }

    // C/D map: col=lane&15, row=(lane>>4)*4+reg [m89-verified]
    float* base = part + (size_t)z * (BSZ * NCOL);
#pragma unroll
    for (int mt = 0; mt < 2; ++mt)
#pragma unroll
        for (int nt = 0; nt < 2; ++nt) {
            int row = bm + (wave >> 1) * 32 + mt * 16 + g * 4;
            int col = bn + (wave & 1) * 32 + nt * 16 + fr;
            float* dst = base + (size_t)row * NCOL + col;
#pragma unroll
            for (int reg = 0; reg < 4; ++reg)
                dst[(size_t)reg * NCOL] = acc[mt][nt][reg];
        }
}

// ---------------------------------------------------------------------------
// Kernel 3: reduce 16 split-K partials, fold scale = exp(lws)/norm * log2e.
// ---------------------------------------------------------------------------
__global__ __launch_bounds__(256) void reduce_kernel(const float* __restrict__ part,
                                                     const float* __restrict__ norm,
                                                     const float* __restrict__ lws,
                                                     float* __restrict__ actv) {
    int i   = blockIdx.x * 256 + threadIdx.x;   // 0..327679
    int col = i % NCOL;
    float s = 0.f;
#pragma unroll
    for (int q = 0; q < KSPLIT; ++q)
        s += part[(size_t)q * (BSZ * NCOL) + i];
    const float scale = __builtin_amdgcn_exp2f(lws[col] * LOG2E) *
                        __builtin_amdgcn_rsqf(norm[col]) * LOG2E;
    actv[i] = s * scale;
}

// ---------------------------------------------------------------------------
// Kernel 4: pairwise L1 -> exp2 -> partial rowsum over 64-wide b2 chunk.
// 256 threads, 2 b-rows/thread. Coalesced f_part stores (NO device-scope
// atomics: write-through to HBM on non-coherent-L2 gfx950, +30us measured).
// ---------------------------------------------------------------------------
__global__ __launch_bounds__(256) void pairwise_kernel(const float* __restrict__ actv,
                                                       float* __restrict__ f_part) {
    const int k   = blockIdx.x;    // 0..127
    const int q   = blockIdx.y;    // 0..7
    const int tid = threadIdx.x;   // 0..255

    __shared__ float sB[64][8];    // 2 KiB, rows 32B-aligned

    for (int i = tid; i < 64 * PP; i += 256) {   // 320 entries
        int r = i / PP;
        int p = i - r * PP;
        sB[r][p] = actv[(size_t)(q * 64 + r) * NCOL + k * PP + p];
    }

    float a[2][PP];
#pragma unroll
    for (int r = 0; r < 2; ++r) {
        const float* ap = &actv[(size_t)(tid + r * 256) * NCOL + k * PP];
#pragma unroll
        for (int p = 0; p < PP; ++p) a[r][p] = ap[p];
    }
    __syncthreads();

    float acc[2] = {0.f, 0.f};
#pragma unroll 4
    for (int j = 0; j < 64; ++j) {
        const float4 v  = *(const float4*)&sB[j][0];
        const float  v4 = sB[j][4];
#pragma unroll
        for (int r = 0; r < 2; ++r) {
            float s = fabsf(a[r][0] - v.x) + fabsf(a[r][1] - v.y) +
                      fabsf(a[r][2] - v.z) + fabsf(a[r][3] - v.w) +
                      fabsf(a[r][4] - v4);
            acc[r] += __builtin_amdgcn_exp2f(-s);   // actv pre-scaled by log2e
        }
    }

    float* fp = f_part + ((size_t)q * KK + k) * BSZ;
    fp[tid]       = acc[0];
    fp[tid + 256] = acc[1];
}

// ---------------------------------------------------------------------------
// Kernel 5: reduce f_part (L2-resident 2MB) into out[:, D:].
// ---------------------------------------------------------------------------
__global__ __launch_bounds__(256) void freduce_kernel(const float* __restrict__ f_part,
                                                      const float* __restrict__ bias,
                                                      float* __restrict__ out) {
    int i = blockIdx.x * 256 + threadIdx.x;   // 0..65535
    int k = i >> 9;
    int b = i & 511;
    float s = 0.f;
#pragma unroll
    for (int q = 0; q < QSPLIT; ++q)
        s += f_part[((size_t)q * KK + k) * BSZ + b];
    out[(size_t)b * OUTW + DD + k] = s - 1.0f + bias[k];
}

// ---------------------------------------------------------------------------
extern "C" void kernel_launch(void* const* d_in, const int* in_sizes, int n_in,
                              void* d_out, int out_size, void* d_ws, size_t ws_size,
                              hipStream_t stream) {
    const float* x     = (const float*)d_in[0];   // [512, 2048]
    const float* theta = (const float*)d_in[1];   // [2048, 128, 5]
    const float* lws   = (const float*)d_in[2];   // [128, 5]
    const float* bias  = (const float*)d_in[3];   // [128]
    float* out = (float*)d_out;                   // [512, 2176]

    float* ws     = (float*)d_ws;
    float* norm   = ws + WS_NORM;
    float* actv   = ws + WS_ACTV;
    float* f_part = ws + WS_FPART;
    ushort* xb    = (ushort*)(ws + WS_XB);
    ushort* thT   = (ushort*)(ws + WS_THT);
    float* part   = ws + WS_PART;

    prep_kernel<<<656, 256, 0, stream>>>(theta, x, norm, thT, xb);
    gemm_kernel<<<1360, 256, 0, stream>>>(xb, thT, part, x, out);
    reduce_kernel<<<(BSZ * NCOL) / 256, 256, 0, stream>>>(part, norm, lws, actv);
    pairwise_kernel<<<dim3(KK, QSPLIT), 256, 0, stream>>>(actv, f_part);
    freduce_kernel<<<256, 256, 0, stream>>>(f_part, bias, out);
}